// Round 2
// 532.899 us; speedup vs baseline: 1.2241x; 1.2241x over previous
//
#include <hip/hip_runtime.h>

#define CDIM 384
#define NTOK 4096
#define NHEAD 12
#define KV_FLOATS (16 * NHEAD * 1024)
#define SCR_FLOATS (KV_FLOATS + 16 * CDIM)   // 202752 = 198*1024

typedef unsigned short ushort_t;
typedef __attribute__((ext_vector_type(8))) short bf16x8;
typedef __attribute__((ext_vector_type(4))) float f32x4;
typedef __attribute__((ext_vector_type(4))) unsigned short u16x4;
typedef __attribute__((ext_vector_type(8))) unsigned short u16x8;

__device__ __attribute__((aligned(16))) float g_scr[SCR_FLOATS];
__device__ int g_flag;

__device__ __forceinline__ float bf2f(ushort_t u) {
  union { unsigned int i; float f; } z; z.i = ((unsigned int)u) << 16; return z.f;
}
__device__ __forceinline__ ushort_t f2bf(float f) {
  union { float f; unsigned int i; } z; z.f = f;
  unsigned int r = z.i + 0x7FFFu + ((z.i >> 16) & 1u);
  return (ushort_t)(r >> 16);
}
__device__ __forceinline__ float ldf(const void* p, size_t i, bool fp32) {
  return fp32 ? ((const float*)p)[i] : bf2f(((const ushort_t*)p)[i]);
}

// load 4 consecutive elements (vectorized) as fp32
__device__ __forceinline__ void load4(const void* src, size_t off, bool fp32, float o[4]) {
  if (fp32) {
    f32x4 v = *(const f32x4*)((const float*)src + off);
    o[0] = v[0]; o[1] = v[1]; o[2] = v[2]; o[3] = v[3];
  } else {
    u16x4 v = *(const u16x4*)((const ushort_t*)src + off);
    o[0] = bf2f(v[0]); o[1] = bf2f(v[1]); o[2] = bf2f(v[2]); o[3] = bf2f(v[3]);
  }
}

// load 8 elements at element-offset off from src, as bf16, 16B-store to dst
__device__ __forceinline__ void stage8(ushort_t* dst, const void* src, size_t off, bool fp32) {
  if (fp32) {
    const float* p = (const float*)src + off;
    f32x4 a = *(const f32x4*)p;
    f32x4 b = *(const f32x4*)(p + 4);
    u16x8 t;
    t[0] = f2bf(a[0]); t[1] = f2bf(a[1]); t[2] = f2bf(a[2]); t[3] = f2bf(a[3]);
    t[4] = f2bf(b[0]); t[5] = f2bf(b[1]); t[6] = f2bf(b[2]); t[7] = f2bf(b[3]);
    *(u16x8*)dst = t;
  } else {
    *(u16x8*)dst = *(const u16x8*)((const ushort_t*)src + off);
  }
}

// 128x128x384 bf16-MFMA GEMM tile (m97 structure), fp32 acc.
__device__ __forceinline__ void gemm128(const void* __restrict__ xsrc, size_t xoff,
                                        const void* __restrict__ wsrc, size_t woff,
                                        bool fp32, ushort_t* xs, ushort_t* wsm,
                                        int tid, f32x4 acc[4][4])
{
  f32x4 zz = {0.f, 0.f, 0.f, 0.f};
  #pragma unroll
  for (int i = 0; i < 4; ++i)
    #pragma unroll
    for (int j = 0; j < 4; ++j) acc[i][j] = zz;

  const int row1 = tid >> 2;
  const int kc   = (tid & 3) << 3;
  const size_t xo0 = xoff + (size_t)row1 * CDIM + kc;
  const size_t xo1 = xo0 + (size_t)64 * CDIM;
  const size_t wo0 = woff + (size_t)row1 * CDIM + kc;
  const size_t wo1 = wo0 + (size_t)64 * CDIM;
  ushort_t* d0 = xs + tid * 8;
  ushort_t* d1 = xs + 2048 + tid * 8;
  ushort_t* d2 = wsm + tid * 8;
  ushort_t* d3 = wsm + 2048 + tid * 8;

  const int lane = tid & 63, quad = lane >> 4, l15 = lane & 15;
  const int wv = tid >> 6, wm = wv >> 1, wn = wv & 1;
  const int arow = (wm * 64 + l15) * 32 + quad * 8;
  const int brow = (wn * 64 + l15) * 32 + quad * 8;

  for (int kk = 0; kk < CDIM; kk += 32) {
    stage8(d0, xsrc, xo0 + kk, fp32);
    stage8(d1, xsrc, xo1 + kk, fp32);
    stage8(d2, wsrc, wo0 + kk, fp32);
    stage8(d3, wsrc, wo1 + kk, fp32);
    __syncthreads();
    bf16x8 aF[4], bF[4];
    #pragma unroll
    for (int i = 0; i < 4; ++i) aF[i] = *(const bf16x8*)(xs + arow + i * 512);
    #pragma unroll
    for (int j = 0; j < 4; ++j) bF[j] = *(const bf16x8*)(wsm + brow + j * 512);
    #pragma unroll
    for (int i = 0; i < 4; ++i)
      #pragma unroll
      for (int j = 0; j < 4; ++j)
        acc[i][j] = __builtin_amdgcn_mfma_f32_16x16x32_bf16(aF[i], bF[j], acc[i][j], 0, 0, 0);
    __syncthreads();
  }
}

// prep: zero scratch + sniff input storage dtype (0 = bf16, 1 = fp32)
__global__ __launch_bounds__(256) void prep(const ushort_t* __restrict__ x) {
  int idx = (blockIdx.x * 256 + threadIdx.x) * 4;
  if (idx < SCR_FLOATS) {
    f32x4 z = {0.f, 0.f, 0.f, 0.f};
    *(f32x4*)(g_scr + idx) = z;
  }
  if (blockIdx.x == 0 && threadIdx.x < 64) {
    ushort_t u = x[threadIdx.x];
    int e = (u >> 7) & 0xFF;
    int ok = (e >= 117 && e <= 136) ? 1 : 0;
    unsigned long long m = __ballot(ok);
    if (threadIdx.x == 0) g_flag = (__popcll(m) >= 52) ? 0 : 1;
  }
}

// Kernel 1: k = elu(x@Wk^T + bk)+1 ; ksum += k (unroped) ; rope(k) ; kv += k_rope^T v
__global__ __launch_bounds__(256) void k1(const void* __restrict__ x,
                                          const void* __restrict__ qkw,
                                          const void* __restrict__ qkb)
{
  __shared__ __align__(16) char smem[33792];
  ushort_t* xs  = (ushort_t*)smem;
  ushort_t* wsm = xs + 4096;
  ushort_t* krope = (ushort_t*)smem;   // reused after GEMM: [128][132] bf16

  const bool fp32 = (g_flag != 0);
  const int tid = threadIdx.x;
  const int nt = blockIdx.x, ct = blockIdx.y, b = blockIdx.z;
  float* kv_g   = g_scr;
  float* ksum_g = g_scr + KV_FLOATS;

  f32x4 acc[4][4];
  gemm128(x,   ((size_t)b * NTOK + (size_t)nt * 128) * CDIM,
          qkw, (size_t)(CDIM + ct * 128) * CDIM, fp32, xs, wsm, tid, acc);

  const int lane = tid & 63, quad = lane >> 4, l15 = lane & 15;
  const int wv = tid >> 6, wm = wv >> 1, wn = wv & 1;

  // bias + elu + 1
  #pragma unroll
  for (int j = 0; j < 4; ++j) {
    const float bj = ldf(qkb, CDIM + ct * 128 + wn * 64 + j * 16 + l15, fp32);
    #pragma unroll
    for (int i = 0; i < 4; ++i)
      #pragma unroll
      for (int r = 0; r < 4; ++r) {
        float v = acc[i][j][r] + bj;
        acc[i][j][r] = v > 0.f ? v + 1.f : __expf(v);
      }
  }

  // unroped column sums -> ksum
  #pragma unroll
  for (int j = 0; j < 4; ++j) {
    float s = 0.f;
    #pragma unroll
    for (int i = 0; i < 4; ++i)
      #pragma unroll
      for (int r = 0; r < 4; ++r) s += acc[i][j][r];
    s += __shfl_down(s, 32);
    s += __shfl_down(s, 16);
    if (lane < 16)
      atomicAdd(&ksum_g[b * CDIM + ct * 128 + wn * 64 + j * 16 + l15], s);
  }

  // rope -> krope (bf16 in LDS, stride 132)
  float th[4]; bool sel[4];
  #pragma unroll
  for (int j = 0; j < 4; ++j) {
    int o = ct * 128 + wn * 64 + j * 16 + l15;
    int p = o >> 1;
    sel[j] = p < 96;
    int jj = sel[j] ? p : p - 96;
    th[j] = exp2f(-0.13841367062030676f * (float)jj);
  }
  #pragma unroll
  for (int i = 0; i < 4; ++i)
    #pragma unroll
    for (int r = 0; r < 4; ++r) {
      const int row  = wm * 64 + i * 16 + quad * 4 + r;
      const int ntok = nt * 128 + row;
      const float hhf = (float)(ntok >> 6), wwf = (float)(ntok & 63);
      #pragma unroll
      for (int j = 0; j < 4; ++j) {
        float ang = (sel[j] ? hhf : wwf) * th[j];
        float sn, cs;
        __sincosf(ang, &sn, &cs);
        float v0 = acc[i][j][r];
        float other = __shfl_xor(v0, 1);
        if (!(lane & 1)) {
          ushort2 t = make_ushort2(f2bf(cs * v0 - sn * other), f2bf(sn * v0 + cs * other));
          *(ushort2*)(krope + row * 132 + wn * 64 + j * 16 + l15) = t;
        }
      }
    }
  __syncthreads();

  // kv[b][h][dd][e] += sum_n k_rope[n][dd] * v[n][e]
  const int hl  = tid >> 6;
  const int ddg = lane >> 3;
  const int eg  = lane & 7;
  const size_t vbase = ((size_t)b * NTOK + (size_t)nt * 128) * CDIM + ct * 128 + hl * 32 + eg * 4;
  const ushort_t* krh = krope + hl * 32 + ddg * 4;
  float kvp[4][4];
  #pragma unroll
  for (int di = 0; di < 4; ++di)
    #pragma unroll
    for (int ei = 0; ei < 4; ++ei) kvp[di][ei] = 0.f;

  #pragma unroll 4
  for (int n = 0; n < 128; ++n) {
    u16x4 kr = *(const u16x4*)(krh + n * 132);
    float kf0 = bf2f(kr[0]), kf1 = bf2f(kr[1]), kf2 = bf2f(kr[2]), kf3 = bf2f(kr[3]);
    float ve0, ve1, ve2, ve3;
    if (fp32) {
      f32x4 vv = *(const f32x4*)((const float*)x + vbase + (size_t)n * CDIM);
      ve0 = vv[0]; ve1 = vv[1]; ve2 = vv[2]; ve3 = vv[3];
    } else {
      u16x4 vv = *(const u16x4*)((const ushort_t*)x + vbase + (size_t)n * CDIM);
      ve0 = bf2f(vv[0]); ve1 = bf2f(vv[1]); ve2 = bf2f(vv[2]); ve3 = bf2f(vv[3]);
    }
    kvp[0][0] += kf0*ve0; kvp[0][1] += kf0*ve1; kvp[0][2] += kf0*ve2; kvp[0][3] += kf0*ve3;
    kvp[1][0] += kf1*ve0; kvp[1][1] += kf1*ve1; kvp[1][2] += kf1*ve2; kvp[1][3] += kf1*ve3;
    kvp[2][0] += kf2*ve0; kvp[2][1] += kf2*ve1; kvp[2][2] += kf2*ve2; kvp[2][3] += kf2*ve3;
    kvp[3][0] += kf3*ve0; kvp[3][1] += kf3*ve1; kvp[3][2] += kf3*ve2; kvp[3][3] += kf3*ve3;
  }
  float* kvdst = kv_g + (size_t)(b * NHEAD + ct * 4 + hl) * 1024 + (ddg * 4) * 32 + eg * 4;
  #pragma unroll
  for (int di = 0; di < 4; ++di)
    #pragma unroll
    for (int ei = 0; ei < 4; ++ei)
      atomicAdd(kvdst + di * 32 + ei, kvp[di][ei]);
}

// Kernel 2: q = elu(x@Wq^T + bq)+1 ; z = 1/(q . kmean + eps) ; rope(q) ;
//           out = z * (q_rope @ kv/n) + LePE(v)   [output dtype = input dtype]
__global__ __launch_bounds__(256) void k2(const void* __restrict__ x,
                                          const void* __restrict__ qkw,
                                          const void* __restrict__ qkb,
                                          const void* __restrict__ lepw,
                                          const void* __restrict__ lepb,
                                          void* __restrict__ out)
{
  __shared__ __align__(16) char smem[50176];
  ushort_t* xs  = (ushort_t*)smem;
  ushort_t* wsm = xs + 4096;
  ushort_t* qr  = (ushort_t*)smem;             // reused after GEMM: [128][136] bf16
  float* lepL = (float*)smem;                  // reused after out-proj: [64][132] fp32 (33792 B)
  ushort_t* kvT = (ushort_t*)(smem + 34816);   // [4][e=32][dd=32] bf16
  float* zl = (float*)(smem + 43008);          // [128][4]
  float* lw = (float*)(smem + 45056);          // [128][9]
  float* lb = (float*)(smem + 49664);          // [128]

  const bool fp32 = (g_flag != 0);
  const int tid = threadIdx.x;
  const int nt = blockIdx.x, ct = blockIdx.y, b = blockIdx.z;
  const float* kv_g   = g_scr;
  const float* ksum_g = g_scr + KV_FLOATS;

  for (int g = tid; g < 1152; g += 256) lw[g] = ldf(lepw, (size_t)ct * 1152 + g, fp32);
  if (tid < 128) lb[tid] = ldf(lepb, ct * 128 + tid, fp32);

  f32x4 acc[4][4];
  gemm128(x,   ((size_t)b * NTOK + (size_t)nt * 128) * CDIM,
          qkw, (size_t)(ct * 128) * CDIM, fp32, xs, wsm, tid, acc);

  const int lane = tid & 63, quad = lane >> 4, l15 = lane & 15;
  const int wv = tid >> 6, wm = wv >> 1, wn = wv & 1;

  // bias + elu + 1
  #pragma unroll
  for (int j = 0; j < 4; ++j) {
    const float bj = ldf(qkb, ct * 128 + wn * 64 + j * 16 + l15, fp32);
    #pragma unroll
    for (int i = 0; i < 4; ++i)
      #pragma unroll
      for (int r = 0; r < 4; ++r) {
        float v = acc[i][j][r] + bj;
        acc[i][j][r] = v > 0.f ? v + 1.f : __expf(v);
      }
  }

  // z = 1/(q . kmean + 1e-6)
  float km[4];
  #pragma unroll
  for (int j = 0; j < 4; ++j)
    km[j] = ksum_g[b * CDIM + ct * 128 + wn * 64 + j * 16 + l15] * (1.f / 4096.f);
  #pragma unroll
  for (int i = 0; i < 4; ++i)
    #pragma unroll
    for (int r = 0; r < 4; ++r) {
      float p0 = acc[i][0][r] * km[0] + acc[i][1][r] * km[1];
      float p1 = acc[i][2][r] * km[2] + acc[i][3][r] * km[3];
      #pragma unroll
      for (int off = 8; off > 0; off >>= 1) {
        p0 += __shfl_down(p0, off, 16);
        p1 += __shfl_down(p1, off, 16);
      }
      if (l15 == 0) {
        int row = wm * 64 + i * 16 + quad * 4 + r;
        zl[row * 4 + wn * 2]     = 1.f / (p0 + 1e-6f);
        zl[row * 4 + wn * 2 + 1] = 1.f / (p1 + 1e-6f);
      }
    }

  // rope -> qr (bf16, stride 136)
  float th[4]; bool sel[4];
  #pragma unroll
  for (int j = 0; j < 4; ++j) {
    int o = ct * 128 + wn * 64 + j * 16 + l15;
    int p = o >> 1;
    sel[j] = p < 96;
    int jj = sel[j] ? p : p - 96;
    th[j] = exp2f(-0.13841367062030676f * (float)jj);
  }
  #pragma unroll
  for (int i = 0; i < 4; ++i)
    #pragma unroll
    for (int r = 0; r < 4; ++r) {
      const int row  = wm * 64 + i * 16 + quad * 4 + r;
      const int ntok = nt * 128 + row;
      const float hhf = (float)(ntok >> 6), wwf = (float)(ntok & 63);
      #pragma unroll
      for (int j = 0; j < 4; ++j) {
        float ang = (sel[j] ? hhf : wwf) * th[j];
        float sn, cs;
        __sincosf(ang, &sn, &cs);
        float v0 = acc[i][j][r];
        float other = __shfl_xor(v0, 1);
        if (!(lane & 1)) {
          ushort2 t = make_ushort2(f2bf(cs * v0 - sn * other), f2bf(sn * v0 + cs * other));
          *(ushort2*)(qr + row * 136 + wn * 64 + j * 16 + l15) = t;
        }
      }
    }

  // stage kv (scaled 1/n) into LDS as bf16 [h][e][dd]
  const float* kvb = kv_g + (size_t)(b * NHEAD + ct * 4) * 1024;
  #pragma unroll
  for (int s = 0; s < 16; ++s) {
    int g = s * 256 + tid;
    int hl2 = g >> 10, dd = (g >> 5) & 31, e = g & 31;
    kvT[hl2 * 1024 + e * 32 + dd] = f2bf(kvb[g] * (1.f / 4096.f));
  }
  __syncthreads();

  // out-projection via MFMA: D[row][e] = q_rope[row][dd] * kv[dd][e], one wave per head
  const int hl = tid >> 6;
  bf16x8 aF[8];
  #pragma unroll
  for (int i = 0; i < 8; ++i)
    aF[i] = *(const bf16x8*)(qr + (i * 16 + l15) * 136 + hl * 32 + quad * 8);
  f32x4 oac[8][2];
  f32x4 zz = {0.f, 0.f, 0.f, 0.f};
  #pragma unroll
  for (int i = 0; i < 8; ++i) { oac[i][0] = zz; oac[i][1] = zz; }
  #pragma unroll
  for (int jn = 0; jn < 2; ++jn) {
    bf16x8 bF = *(const bf16x8*)(kvT + hl * 1024 + (jn * 16 + l15) * 32 + quad * 8);
    #pragma unroll
    for (int i = 0; i < 8; ++i)
      oac[i][jn] = __builtin_amdgcn_mfma_f32_16x16x32_bf16(aF[i], bF, oac[i][jn], 0, 0, 0);
  }
  __syncthreads();   // all waves done reading qr/kvT; qr region free for LePE buffer

  // ---- LePE: two passes (one image row = 64 tokens each), computed into LDS ----
  // thread mapping: cc = tid&31 -> 4 consecutive channels; gg = tid>>5 -> 8 columns
  const int cc  = tid & 31;
  const int ch4 = cc * 4;
  const int gg  = tid >> 5;
  const int w0  = gg * 8;
  const float lbv0 = lb[ch4], lbv1 = lb[ch4 + 1], lbv2 = lb[ch4 + 2], lbv3 = lb[ch4 + 3];

  #pragma unroll
  for (int p = 0; p < 2; ++p) {
    if (p) __syncthreads();          // pass-0 epilogue reads done before overwrite
    const int hh = nt * 2 + p;       // image row of this pass
    float accv[8][4];
    #pragma unroll
    for (int s = 0; s < 8; ++s) {
      accv[s][0] = lbv0; accv[s][1] = lbv1; accv[s][2] = lbv2; accv[s][3] = lbv3;
    }
    #pragma unroll
    for (int rk = 0; rk < 3; ++rk) {
      const int ih = hh + rk - 1;
      if ((unsigned)ih < 64u) {      // wave-uniform branch
        float wr0[4], wr1[4], wr2[4];
        #pragma unroll
        for (int c = 0; c < 4; ++c) {
          wr0[c] = lw[(ch4 + c) * 9 + rk * 3 + 0];
          wr1[c] = lw[(ch4 + c) * 9 + rk * 3 + 1];
          wr2[c] = lw[(ch4 + c) * 9 + rk * 3 + 2];
        }
        const size_t rowbase = ((size_t)b * NTOK + (size_t)(ih * 64)) * CDIM
                             + (size_t)ct * 128 + ch4;
        float av[4], bv[4], cv[4];
        if (w0 > 0) load4(x, rowbase + (size_t)(w0 - 1) * CDIM, fp32, av);
        else { av[0] = av[1] = av[2] = av[3] = 0.f; }
        load4(x, rowbase + (size_t)w0 * CDIM, fp32, bv);
        #pragma unroll
        for (int s = 0; s < 8; ++s) {
          const int iwn = w0 + s + 1;
          if (iwn < 64) load4(x, rowbase + (size_t)iwn * CDIM, fp32, cv);
          else { cv[0] = cv[1] = cv[2] = cv[3] = 0.f; }
          #pragma unroll
          for (int c = 0; c < 4; ++c)
            accv[s][c] += wr0[c] * av[c] + wr1[c] * bv[c] + wr2[c] * cv[c];
          #pragma unroll
          for (int c = 0; c < 4; ++c) { av[c] = bv[c]; bv[c] = cv[c]; }
        }
      }
    }
    #pragma unroll
    for (int s = 0; s < 8; ++s) {
      f32x4 t; t[0] = accv[s][0]; t[1] = accv[s][1]; t[2] = accv[s][2]; t[3] = accv[s][3];
      *(f32x4*)(lepL + (w0 + s) * 132 + ch4) = t;
    }
    __syncthreads();

    // epilogue for rows of this pass: i = p*4 .. p*4+3
    #pragma unroll
    for (int ii = 0; ii < 4; ++ii) {
      const int i = p * 4 + ii;
      #pragma unroll
      for (int jn = 0; jn < 2; ++jn)
        #pragma unroll
        for (int r = 0; r < 4; ++r) {
          const int rloc = ii * 16 + quad * 4 + r;
          const int row  = i * 16 + quad * 4 + r;
          const int e    = jn * 16 + l15;
          const int chl  = hl * 32 + e;
          const int ch   = ct * 128 + chl;
          const int ntok = nt * 128 + row;
          float val = oac[i][jn][r] * zl[row * 4 + hl];
          float lep = lepL[rloc * 132 + chl];
          size_t oi = ((size_t)b * NTOK + ntok) * CDIM + ch;
          float res = val + lep;
          if (fp32) ((float*)out)[oi] = res;
          else      ((ushort_t*)out)[oi] = f2bf(res);
        }
    }
  }
}

extern "C" void kernel_launch(void* const* d_in, const int* in_sizes, int n_in,
                              void* d_out, int out_size, void* d_ws, size_t ws_size,
                              hipStream_t stream) {
  const void* x    = d_in[0];
  const void* qkw  = d_in[1];
  const void* qkb  = d_in[2];
  const void* lepw = d_in[3];
  const void* lepb = d_in[4];

  prep<<<198, 256, 0, stream>>>((const ushort_t*)x);
  dim3 grid(32, 3, 16), blk(256, 1, 1);
  k1<<<grid, blk, 0, stream>>>(x, qkw, qkb);
  k2<<<grid, blk, 0, stream>>>(x, qkw, qkb, lepw, lepb, d_out);
}

// Round 3
// 483.411 us; speedup vs baseline: 1.3494x; 1.1024x over previous
//
#include <hip/hip_runtime.h>

#define CDIM 384
#define NTOK 4096
#define NHEAD 12
#define KV_FLOATS (16 * NHEAD * 1024)
#define SCR_FLOATS (KV_FLOATS + 16 * CDIM)   // 202752

typedef unsigned short ushort_t;
typedef __attribute__((ext_vector_type(8))) short bf16x8;
typedef __attribute__((ext_vector_type(4))) float f32x4;
typedef __attribute__((ext_vector_type(4))) unsigned short u16x4;
typedef __attribute__((ext_vector_type(8))) unsigned short u16x8;

__device__ __attribute__((aligned(16))) float g_scr[SCR_FLOATS];
__device__ __attribute__((aligned(16))) ushort_t g_xbf[(size_t)16 * 4096 * 384];
__device__ __attribute__((aligned(16))) ushort_t g_wbf[768 * 384];
__device__ int g_flag;

__device__ __forceinline__ float bf2f(ushort_t u) {
  union { unsigned int i; float f; } z; z.i = ((unsigned int)u) << 16; return z.f;
}
__device__ __forceinline__ ushort_t f2bf(float f) {
  union { float f; unsigned int i; } z; z.f = f;
  unsigned int r = z.i + 0x7FFFu + ((z.i >> 16) & 1u);
  return (ushort_t)(r >> 16);
}
__device__ __forceinline__ float ldf(const void* p, size_t i, bool fp32) {
  return fp32 ? ((const float*)p)[i] : bf2f(((const ushort_t*)p)[i]);
}

// load 4 consecutive elements (vectorized) as fp32
__device__ __forceinline__ void load4(const void* src, size_t off, bool fp32, float o[4]) {
  if (fp32) {
    f32x4 v = *(const f32x4*)((const float*)src + off);
    o[0] = v[0]; o[1] = v[1]; o[2] = v[2]; o[3] = v[3];
  } else {
    u16x4 v = *(const u16x4*)((const ushort_t*)src + off);
    o[0] = bf2f(v[0]); o[1] = bf2f(v[1]); o[2] = bf2f(v[2]); o[3] = bf2f(v[3]);
  }
}

// read 8 elements at element-offset off, return as bf16x8 (u16x8)
__device__ __forceinline__ u16x8 cvt8(const void* src, size_t off, bool fp32) {
  if (fp32) {
    const float* p = (const float*)src + off;
    f32x4 a = *(const f32x4*)p;
    f32x4 b = *(const f32x4*)(p + 4);
    u16x8 t;
    t[0] = f2bf(a[0]); t[1] = f2bf(a[1]); t[2] = f2bf(a[2]); t[3] = f2bf(a[3]);
    t[4] = f2bf(b[0]); t[5] = f2bf(b[1]); t[6] = f2bf(b[2]); t[7] = f2bf(b[3]);
    return t;
  }
  return *(const u16x8*)((const ushort_t*)src + off);
}

#define GLL16(gp, lp) __builtin_amdgcn_global_load_lds( \
    (const __attribute__((address_space(1))) unsigned int*)(const void*)(gp), \
    (__attribute__((address_space(3))) unsigned int*)(void*)(lp), 16, 0, 0)

// 128x128x384 bf16 MFMA GEMM tile, BK=64, global_load_lds staging from
// pre-swizzled bf16 buffers (chunk' = chunk ^ (row&7) within each 64-k block).
__device__ __forceinline__ void gemm128b(const ushort_t* __restrict__ xg,
                                         const ushort_t* __restrict__ wg,
                                         ushort_t* xs, ushort_t* wsm,
                                         int tid, f32x4 acc[4][4])
{
  f32x4 zz = {0.f, 0.f, 0.f, 0.f};
  #pragma unroll
  for (int i = 0; i < 4; ++i)
    #pragma unroll
    for (int j = 0; j < 4; ++j) acc[i][j] = zz;

  const int lane = tid & 63, quad = lane >> 4, l15 = lane & 15;
  const int wv = tid >> 6, wm = wv >> 1, wn = wv & 1;
  const int srow  = tid >> 3;   // 0..31
  const int sslot = tid & 7;    // 16B chunk within 64-k block
  const int r7  = l15 & 7;
  const int aob = (wm * 64 + l15) * 64;
  const int bob = (wn * 64 + l15) * 64;

  for (int ks = 0; ks < CDIM; ks += 64) {
    #pragma unroll
    for (int r = 0; r < 4; ++r) {
      const int row = r * 32 + srow;
      GLL16(xg + (size_t)row * CDIM + ks + sslot * 8, xs  + (r * 256 + tid) * 8);
      GLL16(wg + (size_t)row * CDIM + ks + sslot * 8, wsm + (r * 256 + tid) * 8);
    }
    __syncthreads();
    #pragma unroll
    for (int h = 0; h < 2; ++h) {
      const int slot = (quad + h * 4) ^ r7;
      bf16x8 aF[4], bF[4];
      #pragma unroll
      for (int i = 0; i < 4; ++i) aF[i] = *(const bf16x8*)(xs + aob + i * 1024 + slot * 8);
      #pragma unroll
      for (int j = 0; j < 4; ++j) bF[j] = *(const bf16x8*)(wsm + bob + j * 1024 + slot * 8);
      #pragma unroll
      for (int i = 0; i < 4; ++i)
        #pragma unroll
        for (int j = 0; j < 4; ++j)
          acc[i][j] = __builtin_amdgcn_mfma_f32_16x16x32_bf16(aF[i], bF[j], acc[i][j], 0, 0, 0);
    }
    __syncthreads();
  }
}

// prep: sniff dtype, zero scratch, convert x/W -> swizzled bf16 buffers
__global__ __launch_bounds__(256) void prep(const void* __restrict__ x,
                                            const void* __restrict__ qkw) {
  __shared__ int sflag;
  const int tid = threadIdx.x;
  if (tid < 64) {
    ushort_t u = ((const ushort_t*)x)[tid];
    int e = (u >> 7) & 0xFF;
    int ok = (e >= 117 && e <= 136) ? 1 : 0;
    unsigned long long m = __ballot(ok);
    if (tid == 0) {
      int f = (__popcll(m) >= 52) ? 0 : 1;
      sflag = f;
      if (blockIdx.x == 0) g_flag = f;
    }
  }
  __syncthreads();
  const bool fp32 = (sflag != 0);
  const int gid = blockIdx.x * 256 + tid;

  if (gid * 4 < SCR_FLOATS) {
    f32x4 z = {0.f, 0.f, 0.f, 0.f};
    *(f32x4*)(g_scr + gid * 4) = z;
  }
  if (gid < 768 * 48) {
    const int oc = gid / 48, ck = gid - oc * 48;
    u16x8 t = cvt8(qkw, (size_t)gid * 8, fp32);
    const int ckp = (ck & ~7) | ((ck & 7) ^ (oc & 7));
    *(u16x8*)(g_wbf + (size_t)oc * CDIM + ckp * 8) = t;
  }
  const int total = 16 * 4096 * 48;
  for (int c = gid; c < total; c += 2048 * 256) {
    const int n = c / 48, ck = c - n * 48;
    u16x8 t = cvt8(x, (size_t)c * 8, fp32);
    const int ckp = (ck & ~7) | ((ck & 7) ^ (n & 7));
    *(u16x8*)(g_xbf + (size_t)n * CDIM + ckp * 8) = t;
  }
}

// Kernel 1: k = elu(x@Wk^T + bk)+1 ; ksum += k (unroped) ; rope(k) ; kv += k_rope^T v
__global__ __launch_bounds__(256) void k1(const void* __restrict__ x,
                                          const void* __restrict__ qkb)
{
  __shared__ __align__(16) char smem[33792];
  ushort_t* xs  = (ushort_t*)smem;
  ushort_t* wsm = xs + 8192;
  ushort_t* krope = (ushort_t*)smem;   // reused after GEMM: [128][132] bf16

  const bool fp32 = (g_flag != 0);
  const int tid = threadIdx.x;
  const int nt = blockIdx.x, ct = blockIdx.y, b = blockIdx.z;
  float* kv_g   = g_scr;
  float* ksum_g = g_scr + KV_FLOATS;

  f32x4 acc[4][4];
  gemm128b(g_xbf + ((size_t)b * NTOK + (size_t)nt * 128) * CDIM,
           g_wbf + (size_t)(CDIM + ct * 128) * CDIM, xs, wsm, tid, acc);

  const int lane = tid & 63, quad = lane >> 4, l15 = lane & 15;
  const int wv = tid >> 6, wm = wv >> 1, wn = wv & 1;

  // bias + elu + 1
  #pragma unroll
  for (int j = 0; j < 4; ++j) {
    const float bj = ldf(qkb, CDIM + ct * 128 + wn * 64 + j * 16 + l15, fp32);
    #pragma unroll
    for (int i = 0; i < 4; ++i)
      #pragma unroll
      for (int r = 0; r < 4; ++r) {
        float v = acc[i][j][r] + bj;
        acc[i][j][r] = v > 0.f ? v + 1.f : __expf(v);
      }
  }

  // unroped column sums -> ksum
  #pragma unroll
  for (int j = 0; j < 4; ++j) {
    float s = 0.f;
    #pragma unroll
    for (int i = 0; i < 4; ++i)
      #pragma unroll
      for (int r = 0; r < 4; ++r) s += acc[i][j][r];
    s += __shfl_down(s, 32);
    s += __shfl_down(s, 16);
    if (lane < 16)
      atomicAdd(&ksum_g[b * CDIM + ct * 128 + wn * 64 + j * 16 + l15], s);
  }

  // rope -> krope (bf16 in LDS, stride 132)
  float th[4]; bool sel[4];
  #pragma unroll
  for (int j = 0; j < 4; ++j) {
    int o = ct * 128 + wn * 64 + j * 16 + l15;
    int p = o >> 1;
    sel[j] = p < 96;
    int jj = sel[j] ? p : p - 96;
    th[j] = exp2f(-0.13841367062030676f * (float)jj);
  }
  #pragma unroll
  for (int i = 0; i < 4; ++i)
    #pragma unroll
    for (int r = 0; r < 4; ++r) {
      const int row  = wm * 64 + i * 16 + quad * 4 + r;
      const int ntok = nt * 128 + row;
      const float hhf = (float)(ntok >> 6), wwf = (float)(ntok & 63);
      #pragma unroll
      for (int j = 0; j < 4; ++j) {
        float ang = (sel[j] ? hhf : wwf) * th[j];
        float sn, cs;
        __sincosf(ang, &sn, &cs);
        float v0 = acc[i][j][r];
        float other = __shfl_xor(v0, 1);
        if (!(lane & 1)) {
          ushort2 t = make_ushort2(f2bf(cs * v0 - sn * other), f2bf(sn * v0 + cs * other));
          *(ushort2*)(krope + row * 132 + wn * 64 + j * 16 + l15) = t;
        }
      }
    }
  __syncthreads();

  // kv[b][h][dd][e] += sum_n k_rope[n][dd] * v[n][e]
  const int hl  = tid >> 6;
  const int ddg = lane >> 3;
  const int eg  = lane & 7;
  const size_t vbase = ((size_t)b * NTOK + (size_t)nt * 128) * CDIM + ct * 128 + hl * 32 + eg * 4;
  const ushort_t* krh = krope + hl * 32 + ddg * 4;
  float kvp[4][4];
  #pragma unroll
  for (int di = 0; di < 4; ++di)
    #pragma unroll
    for (int ei = 0; ei < 4; ++ei) kvp[di][ei] = 0.f;

  #pragma unroll 4
  for (int n = 0; n < 128; ++n) {
    u16x4 kr = *(const u16x4*)(krh + n * 132);
    float kf0 = bf2f(kr[0]), kf1 = bf2f(kr[1]), kf2 = bf2f(kr[2]), kf3 = bf2f(kr[3]);
    float ve0, ve1, ve2, ve3;
    if (fp32) {
      f32x4 vv = *(const f32x4*)((const float*)x + vbase + (size_t)n * CDIM);
      ve0 = vv[0]; ve1 = vv[1]; ve2 = vv[2]; ve3 = vv[3];
    } else {
      u16x4 vv = *(const u16x4*)((const ushort_t*)x + vbase + (size_t)n * CDIM);
      ve0 = bf2f(vv[0]); ve1 = bf2f(vv[1]); ve2 = bf2f(vv[2]); ve3 = bf2f(vv[3]);
    }
    kvp[0][0] += kf0*ve0; kvp[0][1] += kf0*ve1; kvp[0][2] += kf0*ve2; kvp[0][3] += kf0*ve3;
    kvp[1][0] += kf1*ve0; kvp[1][1] += kf1*ve1; kvp[1][2] += kf1*ve2; kvp[1][3] += kf1*ve3;
    kvp[2][0] += kf2*ve0; kvp[2][1] += kf2*ve1; kvp[2][2] += kf2*ve2; kvp[2][3] += kf2*ve3;
    kvp[3][0] += kf3*ve0; kvp[3][1] += kf3*ve1; kvp[3][2] += kf3*ve2; kvp[3][3] += kf3*ve3;
  }
  float* kvdst = kv_g + (size_t)(b * NHEAD + ct * 4 + hl) * 1024 + (ddg * 4) * 32 + eg * 4;
  #pragma unroll
  for (int di = 0; di < 4; ++di)
    #pragma unroll
    for (int ei = 0; ei < 4; ++ei)
      atomicAdd(kvdst + di * 32 + ei, kvp[di][ei]);
}

// Kernel 2: q = elu(x@Wq^T + bq)+1 ; z = 1/(q . kmean + eps) ; rope(q) ;
//           out = z * (q_rope @ kv/n) + LePE(v)
__global__ __launch_bounds__(256) void k2(const void* __restrict__ x,
                                          const void* __restrict__ qkb,
                                          const void* __restrict__ lepw,
                                          const void* __restrict__ lepb,
                                          void* __restrict__ out)
{
  __shared__ __align__(16) char smem[50176];
  ushort_t* xs  = (ushort_t*)smem;
  ushort_t* wsm = xs + 8192;
  ushort_t* qr  = (ushort_t*)smem;             // reused after GEMM: [128][136] bf16
  float* lepL = (float*)smem;                  // reused after out-proj: [64][132] fp32
  ushort_t* kvT = (ushort_t*)(smem + 34816);   // [4][e=32][dd=32] bf16
  float* zl = (float*)(smem + 43008);          // [128][4]
  float* lw = (float*)(smem + 45056);          // [128][9]
  float* lb = (float*)(smem + 49664);          // [128]

  const bool fp32 = (g_flag != 0);
  const int tid = threadIdx.x;
  const int nt = blockIdx.x, ct = blockIdx.y, b = blockIdx.z;
  const float* kv_g   = g_scr;
  const float* ksum_g = g_scr + KV_FLOATS;

  for (int g = tid; g < 1152; g += 256) lw[g] = ldf(lepw, (size_t)ct * 1152 + g, fp32);
  if (tid < 128) lb[tid] = ldf(lepb, ct * 128 + tid, fp32);

  f32x4 acc[4][4];
  gemm128b(g_xbf + ((size_t)b * NTOK + (size_t)nt * 128) * CDIM,
           g_wbf + (size_t)(ct * 128) * CDIM, xs, wsm, tid, acc);

  const int lane = tid & 63, quad = lane >> 4, l15 = lane & 15;
  const int wv = tid >> 6, wm = wv >> 1, wn = wv & 1;

  // bias + elu + 1
  #pragma unroll
  for (int j = 0; j < 4; ++j) {
    const float bj = ldf(qkb, ct * 128 + wn * 64 + j * 16 + l15, fp32);
    #pragma unroll
    for (int i = 0; i < 4; ++i)
      #pragma unroll
      for (int r = 0; r < 4; ++r) {
        float v = acc[i][j][r] + bj;
        acc[i][j][r] = v > 0.f ? v + 1.f : __expf(v);
      }
  }

  // z = 1/(q . kmean + 1e-6)
  float km[4];
  #pragma unroll
  for (int j = 0; j < 4; ++j)
    km[j] = ksum_g[b * CDIM + ct * 128 + wn * 64 + j * 16 + l15] * (1.f / 4096.f);
  #pragma unroll
  for (int i = 0; i < 4; ++i)
    #pragma unroll
    for (int r = 0; r < 4; ++r) {
      float p0 = acc[i][0][r] * km[0] + acc[i][1][r] * km[1];
      float p1 = acc[i][2][r] * km[2] + acc[i][3][r] * km[3];
      #pragma unroll
      for (int off = 8; off > 0; off >>= 1) {
        p0 += __shfl_down(p0, off, 16);
        p1 += __shfl_down(p1, off, 16);
      }
      if (l15 == 0) {
        int row = wm * 64 + i * 16 + quad * 4 + r;
        zl[row * 4 + wn * 2]     = 1.f / (p0 + 1e-6f);
        zl[row * 4 + wn * 2 + 1] = 1.f / (p1 + 1e-6f);
      }
    }

  // rope -> qr (bf16, stride 136)
  float th[4]; bool sel[4];
  #pragma unroll
  for (int j = 0; j < 4; ++j) {
    int o = ct * 128 + wn * 64 + j * 16 + l15;
    int p = o >> 1;
    sel[j] = p < 96;
    int jj = sel[j] ? p : p - 96;
    th[j] = exp2f(-0.13841367062030676f * (float)jj);
  }
  #pragma unroll
  for (int i = 0; i < 4; ++i)
    #pragma unroll
    for (int r = 0; r < 4; ++r) {
      const int row  = wm * 64 + i * 16 + quad * 4 + r;
      const int ntok = nt * 128 + row;
      const float hhf = (float)(ntok >> 6), wwf = (float)(ntok & 63);
      #pragma unroll
      for (int j = 0; j < 4; ++j) {
        float ang = (sel[j] ? hhf : wwf) * th[j];
        float sn, cs;
        __sincosf(ang, &sn, &cs);
        float v0 = acc[i][j][r];
        float other = __shfl_xor(v0, 1);
        if (!(lane & 1)) {
          ushort2 t = make_ushort2(f2bf(cs * v0 - sn * other), f2bf(sn * v0 + cs * other));
          *(ushort2*)(qr + row * 136 + wn * 64 + j * 16 + l15) = t;
        }
      }
    }

  // stage kv (scaled 1/n) into LDS as bf16 [h][e][dd]
  const float* kvb = kv_g + (size_t)(b * NHEAD + ct * 4) * 1024;
  #pragma unroll
  for (int s = 0; s < 16; ++s) {
    int g = s * 256 + tid;
    int hl2 = g >> 10, dd = (g >> 5) & 31, e = g & 31;
    kvT[hl2 * 1024 + e * 32 + dd] = f2bf(kvb[g] * (1.f / 4096.f));
  }
  __syncthreads();

  // out-projection via MFMA
  const int hl = tid >> 6;
  bf16x8 aF[8];
  #pragma unroll
  for (int i = 0; i < 8; ++i)
    aF[i] = *(const bf16x8*)(qr + (i * 16 + l15) * 136 + hl * 32 + quad * 8);
  f32x4 oac[8][2];
  f32x4 zz = {0.f, 0.f, 0.f, 0.f};
  #pragma unroll
  for (int i = 0; i < 8; ++i) { oac[i][0] = zz; oac[i][1] = zz; }
  #pragma unroll
  for (int jn = 0; jn < 2; ++jn) {
    bf16x8 bF = *(const bf16x8*)(kvT + hl * 1024 + (jn * 16 + l15) * 32 + quad * 8);
    #pragma unroll
    for (int i = 0; i < 8; ++i)
      oac[i][jn] = __builtin_amdgcn_mfma_f32_16x16x32_bf16(aF[i], bF, oac[i][jn], 0, 0, 0);
  }
  __syncthreads();   // qr region free for LePE buffer

  // ---- LePE: two passes (one image row = 64 tokens each), into LDS ----
  const int cc  = tid & 31;
  const int ch4 = cc * 4;
  const int gg  = tid >> 5;
  const int w0  = gg * 8;
  const float lbv0 = lb[ch4], lbv1 = lb[ch4 + 1], lbv2 = lb[ch4 + 2], lbv3 = lb[ch4 + 3];

  #pragma unroll
  for (int p = 0; p < 2; ++p) {
    if (p) __syncthreads();
    const int hh = nt * 2 + p;
    float accv[8][4];
    #pragma unroll
    for (int s = 0; s < 8; ++s) {
      accv[s][0] = lbv0; accv[s][1] = lbv1; accv[s][2] = lbv2; accv[s][3] = lbv3;
    }
    #pragma unroll
    for (int rk = 0; rk < 3; ++rk) {
      const int ih = hh + rk - 1;
      if ((unsigned)ih < 64u) {
        float wr0[4], wr1[4], wr2[4];
        #pragma unroll
        for (int c = 0; c < 4; ++c) {
          wr0[c] = lw[(ch4 + c) * 9 + rk * 3 + 0];
          wr1[c] = lw[(ch4 + c) * 9 + rk * 3 + 1];
          wr2[c] = lw[(ch4 + c) * 9 + rk * 3 + 2];
        }
        const size_t rowbase = ((size_t)b * NTOK + (size_t)(ih * 64)) * CDIM
                             + (size_t)ct * 128 + ch4;
        float av[4], bv[4], cv[4];
        if (w0 > 0) load4(x, rowbase + (size_t)(w0 - 1) * CDIM, fp32, av);
        else { av[0] = av[1] = av[2] = av[3] = 0.f; }
        load4(x, rowbase + (size_t)w0 * CDIM, fp32, bv);
        #pragma unroll
        for (int s = 0; s < 8; ++s) {
          const int iwn = w0 + s + 1;
          if (iwn < 64) load4(x, rowbase + (size_t)iwn * CDIM, fp32, cv);
          else { cv[0] = cv[1] = cv[2] = cv[3] = 0.f; }
          #pragma unroll
          for (int c = 0; c < 4; ++c)
            accv[s][c] += wr0[c] * av[c] + wr1[c] * bv[c] + wr2[c] * cv[c];
          #pragma unroll
          for (int c = 0; c < 4; ++c) { av[c] = bv[c]; bv[c] = cv[c]; }
        }
      }
    }
    #pragma unroll
    for (int s = 0; s < 8; ++s) {
      f32x4 t; t[0] = accv[s][0]; t[1] = accv[s][1]; t[2] = accv[s][2]; t[3] = accv[s][3];
      *(f32x4*)(lepL + (w0 + s) * 132 + ch4) = t;
    }
    __syncthreads();

    #pragma unroll
    for (int ii = 0; ii < 4; ++ii) {
      const int i = p * 4 + ii;
      #pragma unroll
      for (int jn = 0; jn < 2; ++jn)
        #pragma unroll
        for (int r = 0; r < 4; ++r) {
          const int rloc = ii * 16 + quad * 4 + r;
          const int row  = i * 16 + quad * 4 + r;
          const int e    = jn * 16 + l15;
          const int chl  = hl * 32 + e;
          const int ch   = ct * 128 + chl;
          const int ntok = nt * 128 + row;
          float val = oac[i][jn][r] * zl[row * 4 + hl];
          float lep = lepL[rloc * 132 + chl];
          size_t oi = ((size_t)b * NTOK + ntok) * CDIM + ch;
          float res = val + lep;
          if (fp32) ((float*)out)[oi] = res;
          else      ((ushort_t*)out)[oi] = f2bf(res);
        }
    }
  }
}

extern "C" void kernel_launch(void* const* d_in, const int* in_sizes, int n_in,
                              void* d_out, int out_size, void* d_ws, size_t ws_size,
                              hipStream_t stream) {
  const void* x    = d_in[0];
  const void* qkw  = d_in[1];
  const void* qkb  = d_in[2];
  const void* lepw = d_in[3];
  const void* lepb = d_in[4];

  prep<<<2048, 256, 0, stream>>>(x, qkw);
  dim3 grid(32, 3, 16), blk(256, 1, 1);
  k1<<<grid, blk, 0, stream>>>(x, qkb);
  k2<<<grid, blk, 0, stream>>>(x, qkb, lepw, lepb, d_out);
}

// Round 4
// 468.322 us; speedup vs baseline: 1.3928x; 1.0322x over previous
//
#include <hip/hip_runtime.h>

#define CDIM 384
#define NTOK 4096
#define NHEAD 12
#define KV_FLOATS (16 * NHEAD * 1024)
#define SCR_FLOATS (KV_FLOATS + 16 * CDIM)   // 202752

typedef unsigned short ushort_t;
typedef __attribute__((ext_vector_type(8))) short bf16x8;
typedef __attribute__((ext_vector_type(4))) float f32x4;
typedef __attribute__((ext_vector_type(4))) unsigned short u16x4;
typedef __attribute__((ext_vector_type(8))) unsigned short u16x8;

__device__ __attribute__((aligned(16))) float g_scr[SCR_FLOATS];
__device__ __attribute__((aligned(16))) ushort_t g_xbf[(size_t)16 * 4096 * 384];
__device__ __attribute__((aligned(16))) ushort_t g_wbf[768 * 384];
__device__ __attribute__((aligned(16))) float g_part[(size_t)16 * 3 * 32 * 4096];   // per-block kv partials
__device__ __attribute__((aligned(16))) float g_kspart[(size_t)16 * 3 * 32 * 256];  // per-block ksum partials
__device__ int g_flag;

__device__ __forceinline__ float bf2f(ushort_t u) {
  union { unsigned int i; float f; } z; z.i = ((unsigned int)u) << 16; return z.f;
}
__device__ __forceinline__ ushort_t f2bf(float f) {
  union { float f; unsigned int i; } z; z.f = f;
  unsigned int r = z.i + 0x7FFFu + ((z.i >> 16) & 1u);
  return (ushort_t)(r >> 16);
}
__device__ __forceinline__ float ldf(const void* p, size_t i, bool fp32) {
  return fp32 ? ((const float*)p)[i] : bf2f(((const ushort_t*)p)[i]);
}

__device__ __forceinline__ void load4(const void* src, size_t off, bool fp32, float o[4]) {
  if (fp32) {
    f32x4 v = *(const f32x4*)((const float*)src + off);
    o[0] = v[0]; o[1] = v[1]; o[2] = v[2]; o[3] = v[3];
  } else {
    u16x4 v = *(const u16x4*)((const ushort_t*)src + off);
    o[0] = bf2f(v[0]); o[1] = bf2f(v[1]); o[2] = bf2f(v[2]); o[3] = bf2f(v[3]);
  }
}

__device__ __forceinline__ u16x8 cvt8(const void* src, size_t off, bool fp32) {
  if (fp32) {
    const float* p = (const float*)src + off;
    f32x4 a = *(const f32x4*)p;
    f32x4 b = *(const f32x4*)(p + 4);
    u16x8 t;
    t[0] = f2bf(a[0]); t[1] = f2bf(a[1]); t[2] = f2bf(a[2]); t[3] = f2bf(a[3]);
    t[4] = f2bf(b[0]); t[5] = f2bf(b[1]); t[6] = f2bf(b[2]); t[7] = f2bf(b[3]);
    return t;
  }
  return *(const u16x8*)((const ushort_t*)src + off);
}

#define GLL16(gp, lp) __builtin_amdgcn_global_load_lds( \
    (const __attribute__((address_space(1))) unsigned int*)(const void*)(gp), \
    (__attribute__((address_space(3))) unsigned int*)(void*)(lp), 16, 0, 0)

// 128x128x384 bf16 MFMA GEMM tile. BK=32, double-buffered LDS (2 x 16KB),
// raw barriers + counted vmcnt so prefetch loads stay in flight across barriers.
// Source buffers are pre-swizzled: 16B chunk c within each 32-k group stored at
// c ^ (row & 3); ds_read XORs the same on the way out (both-sides swizzle).
__device__ __forceinline__ void gemm128c(const ushort_t* __restrict__ xg,
                                         const ushort_t* __restrict__ wg,
                                         ushort_t* lds, int tid, f32x4 acc[4][4])
{
  f32x4 zz = {0.f, 0.f, 0.f, 0.f};
  #pragma unroll
  for (int i = 0; i < 4; ++i)
    #pragma unroll
    for (int j = 0; j < 4; ++j) acc[i][j] = zz;

  const int lane = tid & 63, quad = lane >> 4, l15 = lane & 15;
  const int wv = tid >> 6, wm = wv >> 1, wn = wv & 1;
  const int srow = tid >> 2;        // 0..63
  const int sc   = tid & 3;         // 16B chunk within 32-k block
  const int sx   = l15 & 3;         // read-side XOR

  const ushort_t* xa = xg + (size_t)srow * CDIM + sc * 8;
  const ushort_t* wa = wg + (size_t)srow * CDIM + sc * 8;

  // stage step ks into buffer buf (A: 4096 ushorts, B: 4096 ushorts)
  #define STAGE_STEP(buf, ks) do {                                   \
    ushort_t* la_ = lds + (buf) * 8192;                              \
    ushort_t* lb_ = la_ + 4096;                                      \
    GLL16(xa + (ks),                  la_ + tid * 8);                \
    GLL16(xa + (ks) + 64 * CDIM,      la_ + 2048 + tid * 8);         \
    GLL16(wa + (ks),                  lb_ + tid * 8);                \
    GLL16(wa + (ks) + 64 * CDIM,      lb_ + 2048 + tid * 8);         \
  } while (0)

  STAGE_STEP(0, 0);
  #pragma unroll
  for (int s = 0; s < 12; ++s) {
    const int cur = s & 1;
    if (s < 11) {
      STAGE_STEP(cur ^ 1, (s + 1) * 32);
      asm volatile("s_waitcnt vmcnt(4)" ::: "memory");
    } else {
      asm volatile("s_waitcnt vmcnt(0)" ::: "memory");
    }
    __builtin_amdgcn_s_barrier();
    asm volatile("" ::: "memory");
    const ushort_t* la = lds + cur * 8192;
    const ushort_t* lb = la + 4096;
    bf16x8 aF[4], bF[4];
    #pragma unroll
    for (int i = 0; i < 4; ++i)
      aF[i] = *(const bf16x8*)(la + (wm * 64 + l15) * 32 + i * 512 + (quad ^ sx) * 8);
    #pragma unroll
    for (int j = 0; j < 4; ++j)
      bF[j] = *(const bf16x8*)(lb + (wn * 64 + l15) * 32 + j * 512 + (quad ^ sx) * 8);
    #pragma unroll
    for (int i = 0; i < 4; ++i)
      #pragma unroll
      for (int j = 0; j < 4; ++j)
        acc[i][j] = __builtin_amdgcn_mfma_f32_16x16x32_bf16(aF[i], bF[j], acc[i][j], 0, 0, 0);
    asm volatile("" ::: "memory");
    __builtin_amdgcn_s_barrier();
  }
  #undef STAGE_STEP
}

// prep: sniff dtype, convert x/W -> swizzled bf16 buffers (chunk c -> c^(row&3))
__global__ __launch_bounds__(256) void prep(const void* __restrict__ x,
                                            const void* __restrict__ qkw) {
  __shared__ int sflag;
  const int tid = threadIdx.x;
  if (tid < 64) {
    ushort_t u = ((const ushort_t*)x)[tid];
    int e = (u >> 7) & 0xFF;
    int ok = (e >= 117 && e <= 136) ? 1 : 0;
    unsigned long long m = __ballot(ok);
    if (tid == 0) {
      int f = (__popcll(m) >= 52) ? 0 : 1;
      sflag = f;
      if (blockIdx.x == 0) g_flag = f;
    }
  }
  __syncthreads();
  const bool fp32 = (sflag != 0);
  const int gid = blockIdx.x * 256 + tid;

  if (gid < 768 * 48) {
    const int oc = gid / 48, ck = gid - oc * 48;
    u16x8 t = cvt8(qkw, (size_t)gid * 8, fp32);
    const int ckp = (ck & ~3) | ((ck & 3) ^ (oc & 3));
    *(u16x8*)(g_wbf + (size_t)oc * CDIM + ckp * 8) = t;
  }
  const int total = 16 * 4096 * 48;
  for (int c = gid; c < total; c += 2048 * 256) {
    const int n = c / 48, ck = c - n * 48;
    u16x8 t = cvt8(x, (size_t)c * 8, fp32);
    const int ckp = (ck & ~3) | ((ck & 3) ^ (n & 3));
    *(u16x8*)(g_xbf + (size_t)n * CDIM + ckp * 8) = t;
  }
}

// Kernel 1: k = elu(x@Wk^T + bk)+1 ; ksum partial ; rope(k) ; kv partial = k_rope^T v
__global__ __launch_bounds__(256) void k1(const void* __restrict__ x,
                                          const void* __restrict__ qkb)
{
  __shared__ __align__(16) char smem[33792];
  ushort_t* xs = (ushort_t*)smem;      // gemm dbuf: 32KB
  ushort_t* krope = (ushort_t*)smem;   // reused after GEMM: [128][132] bf16

  const bool fp32 = (g_flag != 0);
  const int tid = threadIdx.x;
  const int nt = blockIdx.x, ct = blockIdx.y, b = blockIdx.z;

  f32x4 acc[4][4];
  gemm128c(g_xbf + ((size_t)b * NTOK + (size_t)nt * 128) * CDIM,
           g_wbf + (size_t)(CDIM + ct * 128) * CDIM, xs, tid, acc);

  const int lane = tid & 63, quad = lane >> 4, l15 = lane & 15;
  const int wv = tid >> 6, wm = wv >> 1, wn = wv & 1;

  // bias + elu + 1
  #pragma unroll
  for (int j = 0; j < 4; ++j) {
    const float bj = ldf(qkb, CDIM + ct * 128 + wn * 64 + j * 16 + l15, fp32);
    #pragma unroll
    for (int i = 0; i < 4; ++i)
      #pragma unroll
      for (int r = 0; r < 4; ++r) {
        float v = acc[i][j][r] + bj;
        acc[i][j][r] = v > 0.f ? v + 1.f : __expf(v);
      }
  }

  // unroped column sums -> ksum partial (plain store, no atomics)
  #pragma unroll
  for (int j = 0; j < 4; ++j) {
    float s = 0.f;
    #pragma unroll
    for (int i = 0; i < 4; ++i)
      #pragma unroll
      for (int r = 0; r < 4; ++r) s += acc[i][j][r];
    s += __shfl_down(s, 32);
    s += __shfl_down(s, 16);
    if (lane < 16)
      g_kspart[(size_t)(((b * 3 + ct) * 32 + nt) * 2 + wm) * 128 + wn * 64 + j * 16 + l15] = s;
  }

  // rope -> krope (bf16 in LDS, stride 132)
  float th[4]; bool sel[4];
  #pragma unroll
  for (int j = 0; j < 4; ++j) {
    int o = ct * 128 + wn * 64 + j * 16 + l15;
    int p = o >> 1;
    sel[j] = p < 96;
    int jj = sel[j] ? p : p - 96;
    th[j] = exp2f(-0.13841367062030676f * (float)jj);
  }
  #pragma unroll
  for (int i = 0; i < 4; ++i)
    #pragma unroll
    for (int r = 0; r < 4; ++r) {
      const int row  = wm * 64 + i * 16 + quad * 4 + r;
      const int ntok = nt * 128 + row;
      const float hhf = (float)(ntok >> 6), wwf = (float)(ntok & 63);
      #pragma unroll
      for (int j = 0; j < 4; ++j) {
        float ang = (sel[j] ? hhf : wwf) * th[j];
        float sn, cs;
        __sincosf(ang, &sn, &cs);
        float v0 = acc[i][j][r];
        float other = __shfl_xor(v0, 1);
        if (!(lane & 1)) {
          ushort2 t = make_ushort2(f2bf(cs * v0 - sn * other), f2bf(sn * v0 + cs * other));
          *(ushort2*)(krope + row * 132 + wn * 64 + j * 16 + l15) = t;
        }
      }
    }
  __syncthreads();

  // kv partial [b][ct][nt][h][dd][e] = sum_n k_rope[n][dd] * v[n][e]
  const int hl  = tid >> 6;
  const int ddg = lane >> 3;
  const int eg  = lane & 7;
  const size_t vbase = ((size_t)b * NTOK + (size_t)nt * 128) * CDIM + ct * 128 + hl * 32 + eg * 4;
  const ushort_t* krh = krope + hl * 32 + ddg * 4;
  float kvp[4][4];
  #pragma unroll
  for (int di = 0; di < 4; ++di)
    #pragma unroll
    for (int ei = 0; ei < 4; ++ei) kvp[di][ei] = 0.f;

  #pragma unroll 4
  for (int n = 0; n < 128; ++n) {
    u16x4 kr = *(const u16x4*)(krh + n * 132);
    float kf0 = bf2f(kr[0]), kf1 = bf2f(kr[1]), kf2 = bf2f(kr[2]), kf3 = bf2f(kr[3]);
    float ve0, ve1, ve2, ve3;
    if (fp32) {
      f32x4 vv = *(const f32x4*)((const float*)x + vbase + (size_t)n * CDIM);
      ve0 = vv[0]; ve1 = vv[1]; ve2 = vv[2]; ve3 = vv[3];
    } else {
      u16x4 vv = *(const u16x4*)((const ushort_t*)x + vbase + (size_t)n * CDIM);
      ve0 = bf2f(vv[0]); ve1 = bf2f(vv[1]); ve2 = bf2f(vv[2]); ve3 = bf2f(vv[3]);
    }
    kvp[0][0] += kf0*ve0; kvp[0][1] += kf0*ve1; kvp[0][2] += kf0*ve2; kvp[0][3] += kf0*ve3;
    kvp[1][0] += kf1*ve0; kvp[1][1] += kf1*ve1; kvp[1][2] += kf1*ve2; kvp[1][3] += kf1*ve3;
    kvp[2][0] += kf2*ve0; kvp[2][1] += kf2*ve1; kvp[2][2] += kf2*ve2; kvp[2][3] += kf2*ve3;
    kvp[3][0] += kf3*ve0; kvp[3][1] += kf3*ve1; kvp[3][2] += kf3*ve2; kvp[3][3] += kf3*ve3;
  }
  float* dst = g_part + ((size_t)(((b * 3 + ct) * 32 + nt) * 4 + hl)) * 1024 + ddg * 128 + eg * 4;
  #pragma unroll
  for (int di = 0; di < 4; ++di) {
    f32x4 t; t[0] = kvp[di][0]; t[1] = kvp[di][1]; t[2] = kvp[di][2]; t[3] = kvp[di][3];
    *(f32x4*)(dst + di * 32) = t;
  }
}

// reduction: kv = sum_nt partials ; ksum = sum_{nt,wm} partials
__global__ __launch_bounds__(256) void red() {
  const int t = blockIdx.x * 256 + threadIdx.x;
  if (blockIdx.x < 192) {
    const int o = t * 4;
    const int b = o / 12288, r = o - b * 12288;
    const int h = r >> 10, off = r & 1023;
    const int ct = h >> 2, hl = h & 3;
    const float* p = g_part + ((size_t)((b * 3 + ct) * 32) * 4 + hl) * 1024 + off;
    f32x4 s = {0.f, 0.f, 0.f, 0.f};
    #pragma unroll 8
    for (int nt = 0; nt < 32; ++nt) {
      f32x4 v = *(const f32x4*)(p + (size_t)nt * 4096);
      s[0] += v[0]; s[1] += v[1]; s[2] += v[2]; s[3] += v[3];
    }
    *(f32x4*)(g_scr + (size_t)b * 12288 + h * 1024 + off) = s;
  } else {
    const int s4 = (t - 192 * 256) * 4;
    if (s4 < 16 * 384) {
      const int b = s4 / 384, ch = s4 - b * 384;
      const int ct = ch >> 7, chl = ch & 127;
      const float* p = g_kspart + (size_t)((b * 3 + ct) * 32) * 256 + chl;
      f32x4 s = {0.f, 0.f, 0.f, 0.f};
      #pragma unroll 8
      for (int nt = 0; nt < 32; ++nt) {
        f32x4 v0 = *(const f32x4*)(p + nt * 256);
        f32x4 v1 = *(const f32x4*)(p + nt * 256 + 128);
        s[0] += v0[0] + v1[0]; s[1] += v0[1] + v1[1];
        s[2] += v0[2] + v1[2]; s[3] += v0[3] + v1[3];
      }
      *(f32x4*)(g_scr + KV_FLOATS + (size_t)b * 384 + ch) = s;
    }
  }
}

// Kernel 2: q = elu(x@Wq^T + bq)+1 ; z = 1/(q . kmean + eps) ; rope(q) ;
//           out = z * (q_rope @ kv/n) + LePE(v)
__global__ __launch_bounds__(256) void k2(const void* __restrict__ x,
                                          const void* __restrict__ qkb,
                                          const void* __restrict__ lepw,
                                          const void* __restrict__ lepb,
                                          void* __restrict__ out)
{
  __shared__ __align__(16) char smem[50176];
  ushort_t* xs  = (ushort_t*)smem;             // gemm dbuf: 32KB
  ushort_t* qr  = (ushort_t*)smem;             // reused after GEMM: [128][136] bf16
  float* lepL = (float*)smem;                  // reused after out-proj: [64][132] fp32
  ushort_t* kvT = (ushort_t*)(smem + 34816);   // [4][e=32][dd=32] bf16
  float* zl = (float*)(smem + 43008);          // [128][4]
  float* lw = (float*)(smem + 45056);          // [128][9]
  float* lb = (float*)(smem + 49664);          // [128]

  const bool fp32 = (g_flag != 0);
  const int tid = threadIdx.x;
  const int nt = blockIdx.x, ct = blockIdx.y, b = blockIdx.z;
  const float* kv_g   = g_scr;
  const float* ksum_g = g_scr + KV_FLOATS;

  for (int g = tid; g < 1152; g += 256) lw[g] = ldf(lepw, (size_t)ct * 1152 + g, fp32);
  if (tid < 128) lb[tid] = ldf(lepb, ct * 128 + tid, fp32);

  f32x4 acc[4][4];
  gemm128c(g_xbf + ((size_t)b * NTOK + (size_t)nt * 128) * CDIM,
           g_wbf + (size_t)(ct * 128) * CDIM, xs, tid, acc);

  const int lane = tid & 63, quad = lane >> 4, l15 = lane & 15;
  const int wv = tid >> 6, wm = wv >> 1, wn = wv & 1;

  // bias + elu + 1
  #pragma unroll
  for (int j = 0; j < 4; ++j) {
    const float bj = ldf(qkb, ct * 128 + wn * 64 + j * 16 + l15, fp32);
    #pragma unroll
    for (int i = 0; i < 4; ++i)
      #pragma unroll
      for (int r = 0; r < 4; ++r) {
        float v = acc[i][j][r] + bj;
        acc[i][j][r] = v > 0.f ? v + 1.f : __expf(v);
      }
  }

  // z = 1/(q . kmean + 1e-6)
  float km[4];
  #pragma unroll
  for (int j = 0; j < 4; ++j)
    km[j] = ksum_g[b * CDIM + ct * 128 + wn * 64 + j * 16 + l15] * (1.f / 4096.f);
  #pragma unroll
  for (int i = 0; i < 4; ++i)
    #pragma unroll
    for (int r = 0; r < 4; ++r) {
      float p0 = acc[i][0][r] * km[0] + acc[i][1][r] * km[1];
      float p1 = acc[i][2][r] * km[2] + acc[i][3][r] * km[3];
      #pragma unroll
      for (int off = 8; off > 0; off >>= 1) {
        p0 += __shfl_down(p0, off, 16);
        p1 += __shfl_down(p1, off, 16);
      }
      if (l15 == 0) {
        int row = wm * 64 + i * 16 + quad * 4 + r;
        zl[row * 4 + wn * 2]     = 1.f / (p0 + 1e-6f);
        zl[row * 4 + wn * 2 + 1] = 1.f / (p1 + 1e-6f);
      }
    }

  // rope -> qr (bf16, stride 136)
  float th[4]; bool sel[4];
  #pragma unroll
  for (int j = 0; j < 4; ++j) {
    int o = ct * 128 + wn * 64 + j * 16 + l15;
    int p = o >> 1;
    sel[j] = p < 96;
    int jj = sel[j] ? p : p - 96;
    th[j] = exp2f(-0.13841367062030676f * (float)jj);
  }
  #pragma unroll
  for (int i = 0; i < 4; ++i)
    #pragma unroll
    for (int r = 0; r < 4; ++r) {
      const int row  = wm * 64 + i * 16 + quad * 4 + r;
      const int ntok = nt * 128 + row;
      const float hhf = (float)(ntok >> 6), wwf = (float)(ntok & 63);
      #pragma unroll
      for (int j = 0; j < 4; ++j) {
        float ang = (sel[j] ? hhf : wwf) * th[j];
        float sn, cs;
        __sincosf(ang, &sn, &cs);
        float v0 = acc[i][j][r];
        float other = __shfl_xor(v0, 1);
        if (!(lane & 1)) {
          ushort2 t = make_ushort2(f2bf(cs * v0 - sn * other), f2bf(sn * v0 + cs * other));
          *(ushort2*)(qr + row * 136 + wn * 64 + j * 16 + l15) = t;
        }
      }
    }

  // stage kv (scaled 1/n) into LDS as bf16 [h][e][dd]
  const float* kvb = kv_g + (size_t)(b * NHEAD + ct * 4) * 1024;
  #pragma unroll
  for (int s = 0; s < 16; ++s) {
    int g = s * 256 + tid;
    int hl2 = g >> 10, dd = (g >> 5) & 31, e = g & 31;
    kvT[hl2 * 1024 + e * 32 + dd] = f2bf(kvb[g] * (1.f / 4096.f));
  }
  __syncthreads();

  // out-projection via MFMA
  const int hl = tid >> 6;
  bf16x8 aF[8];
  #pragma unroll
  for (int i = 0; i < 8; ++i)
    aF[i] = *(const bf16x8*)(qr + (i * 16 + l15) * 136 + hl * 32 + quad * 8);
  f32x4 oac[8][2];
  f32x4 zz = {0.f, 0.f, 0.f, 0.f};
  #pragma unroll
  for (int i = 0; i < 8; ++i) { oac[i][0] = zz; oac[i][1] = zz; }
  #pragma unroll
  for (int jn = 0; jn < 2; ++jn) {
    bf16x8 bF = *(const bf16x8*)(kvT + hl * 1024 + (jn * 16 + l15) * 32 + quad * 8);
    #pragma unroll
    for (int i = 0; i < 8; ++i)
      oac[i][jn] = __builtin_amdgcn_mfma_f32_16x16x32_bf16(aF[i], bF, oac[i][jn], 0, 0, 0);
  }
  __syncthreads();   // qr region free for LePE buffer

  // ---- LePE: two passes (one image row = 64 tokens each), into LDS ----
  const int cc  = tid & 31;
  const int ch4 = cc * 4;
  const int gg  = tid >> 5;
  const int w0  = gg * 8;
  const float lbv0 = lb[ch4], lbv1 = lb[ch4 + 1], lbv2 = lb[ch4 + 2], lbv3 = lb[ch4 + 3];

  #pragma unroll
  for (int p = 0; p < 2; ++p) {
    if (p) __syncthreads();
    const int hh = nt * 2 + p;
    float accv[8][4];
    #pragma unroll
    for (int s = 0; s < 8; ++s) {
      accv[s][0] = lbv0; accv[s][1] = lbv1; accv[s][2] = lbv2; accv[s][3] = lbv3;
    }
    #pragma unroll
    for (int rk = 0; rk < 3; ++rk) {
      const int ih = hh + rk - 1;
      if ((unsigned)ih < 64u) {
        float wr0[4], wr1[4], wr2[4];
        #pragma unroll
        for (int c = 0; c < 4; ++c) {
          wr0[c] = lw[(ch4 + c) * 9 + rk * 3 + 0];
          wr1[c] = lw[(ch4 + c) * 9 + rk * 3 + 1];
          wr2[c] = lw[(ch4 + c) * 9 + rk * 3 + 2];
        }
        const size_t rowbase = ((size_t)b * NTOK + (size_t)(ih * 64)) * CDIM
                             + (size_t)ct * 128 + ch4;
        float av[4], bv[4], cv[4];
        if (w0 > 0) load4(x, rowbase + (size_t)(w0 - 1) * CDIM, fp32, av);
        else { av[0] = av[1] = av[2] = av[3] = 0.f; }
        load4(x, rowbase + (size_t)w0 * CDIM, fp32, bv);
        #pragma unroll
        for (int s = 0; s < 8; ++s) {
          const int iwn = w0 + s + 1;
          if (iwn < 64) load4(x, rowbase + (size_t)iwn * CDIM, fp32, cv);
          else { cv[0] = cv[1] = cv[2] = cv[3] = 0.f; }
          #pragma unroll
          for (int c = 0; c < 4; ++c)
            accv[s][c] += wr0[c] * av[c] + wr1[c] * bv[c] + wr2[c] * cv[c];
          #pragma unroll
          for (int c = 0; c < 4; ++c) { av[c] = bv[c]; bv[c] = cv[c]; }
        }
      }
    }
    #pragma unroll
    for (int s = 0; s < 8; ++s) {
      f32x4 t; t[0] = accv[s][0]; t[1] = accv[s][1]; t[2] = accv[s][2]; t[3] = accv[s][3];
      *(f32x4*)(lepL + (w0 + s) * 132 + ch4) = t;
    }
    __syncthreads();

    #pragma unroll
    for (int ii = 0; ii < 4; ++ii) {
      const int i = p * 4 + ii;
      #pragma unroll
      for (int jn = 0; jn < 2; ++jn)
        #pragma unroll
        for (int r = 0; r < 4; ++r) {
          const int rloc = ii * 16 + quad * 4 + r;
          const int row  = i * 16 + quad * 4 + r;
          const int e    = jn * 16 + l15;
          const int chl  = hl * 32 + e;
          const int ch   = ct * 128 + chl;
          const int ntok = nt * 128 + row;
          float val = oac[i][jn][r] * zl[row * 4 + hl];
          float lep = lepL[rloc * 132 + chl];
          size_t oi = ((size_t)b * NTOK + ntok) * CDIM + ch;
          float res = val + lep;
          if (fp32) ((float*)out)[oi] = res;
          else      ((ushort_t*)out)[oi] = f2bf(res);
        }
    }
  }
}

extern "C" void kernel_launch(void* const* d_in, const int* in_sizes, int n_in,
                              void* d_out, int out_size, void* d_ws, size_t ws_size,
                              hipStream_t stream) {
  const void* x    = d_in[0];
  const void* qkw  = d_in[1];
  const void* qkb  = d_in[2];
  const void* lepw = d_in[3];
  const void* lepb = d_in[4];

  prep<<<2048, 256, 0, stream>>>(x, qkw);
  dim3 grid(32, 3, 16), blk(256, 1, 1);
  k1<<<grid, blk, 0, stream>>>(x, qkb);
  red<<<198, 256, 0, stream>>>();
  k2<<<grid, blk, 0, stream>>>(x, qkb, lepw, lepb, d_out);
}

// Round 5
// 356.002 us; speedup vs baseline: 1.8323x; 1.3155x over previous
//
#include <hip/hip_runtime.h>

#define CDIM 384
#define NTOK 4096
#define NHEAD 12
#define KV_FLOATS (16 * NHEAD * 1024)
#define SCR_FLOATS (KV_FLOATS + 16 * CDIM)   // 202752

typedef unsigned short ushort_t;
typedef __attribute__((ext_vector_type(8))) short bf16x8;
typedef __attribute__((ext_vector_type(4))) float f32x4;
typedef __attribute__((ext_vector_type(4))) unsigned short u16x4;
typedef __attribute__((ext_vector_type(8))) unsigned short u16x8;

__device__ __attribute__((aligned(16))) float g_scr[SCR_FLOATS];
__device__ __attribute__((aligned(16))) ushort_t g_xbf[(size_t)16 * 4096 * 384];
__device__ __attribute__((aligned(16))) ushort_t g_wbf[768 * 384];
__device__ __attribute__((aligned(16))) float g_part[(size_t)16 * 3 * 32 * 4096];   // per-block kv partials
__device__ __attribute__((aligned(16))) float g_kspart[(size_t)16 * 3 * 32 * 256];  // per-block ksum partials
__device__ int g_flag;

__device__ __forceinline__ float bf2f(ushort_t u) {
  union { unsigned int i; float f; } z; z.i = ((unsigned int)u) << 16; return z.f;
}
__device__ __forceinline__ ushort_t f2bf(float f) {
  union { float f; unsigned int i; } z; z.f = f;
  unsigned int r = z.i + 0x7FFFu + ((z.i >> 16) & 1u);
  return (ushort_t)(r >> 16);
}
__device__ __forceinline__ float ldf(const void* p, size_t i, bool fp32) {
  return fp32 ? ((const float*)p)[i] : bf2f(((const ushort_t*)p)[i]);
}

__device__ __forceinline__ void load4(const void* src, size_t off, bool fp32, float o[4]) {
  if (fp32) {
    f32x4 v = *(const f32x4*)((const float*)src + off);
    o[0] = v[0]; o[1] = v[1]; o[2] = v[2]; o[3] = v[3];
  } else {
    u16x4 v = *(const u16x4*)((const ushort_t*)src + off);
    o[0] = bf2f(v[0]); o[1] = bf2f(v[1]); o[2] = bf2f(v[2]); o[3] = bf2f(v[3]);
  }
}

__device__ __forceinline__ u16x8 cvt8(const void* src, size_t off, bool fp32) {
  if (fp32) {
    const float* p = (const float*)src + off;
    f32x4 a = *(const f32x4*)p;
    f32x4 b = *(const f32x4*)(p + 4);
    u16x8 t;
    t[0] = f2bf(a[0]); t[1] = f2bf(a[1]); t[2] = f2bf(a[2]); t[3] = f2bf(a[3]);
    t[4] = f2bf(b[0]); t[5] = f2bf(b[1]); t[6] = f2bf(b[2]); t[7] = f2bf(b[3]);
    return t;
  }
  return *(const u16x8*)((const ushort_t*)src + off);
}

#define GLL16(gp, lp) __builtin_amdgcn_global_load_lds( \
    (const __attribute__((address_space(1))) unsigned int*)(const void*)(gp), \
    (__attribute__((address_space(3))) unsigned int*)(void*)(lp), 16, 0, 0)

// 128x128x384 bf16 MFMA GEMM tile. BK=32, double-buffered LDS (2 x 16KB),
// raw barriers + counted vmcnt so prefetch loads stay in flight across barriers.
// Pre-swizzle: 16B chunk c within each 32-k group stored at c ^ ((row>>1)&3);
// read-side XOR matches -> 2 lanes/bank (free).
__device__ __forceinline__ void gemm128c(const ushort_t* __restrict__ xg,
                                         const ushort_t* __restrict__ wg,
                                         ushort_t* lds, int tid, f32x4 acc[4][4])
{
  f32x4 zz = {0.f, 0.f, 0.f, 0.f};
  #pragma unroll
  for (int i = 0; i < 4; ++i)
    #pragma unroll
    for (int j = 0; j < 4; ++j) acc[i][j] = zz;

  const int lane = tid & 63, quad = lane >> 4, l15 = lane & 15;
  const int wv = tid >> 6, wm = wv >> 1, wn = wv & 1;
  const int srow = tid >> 2;        // 0..63
  const int sc   = tid & 3;         // 16B chunk within 32-k block
  const int sx   = (l15 >> 1) & 3;  // read-side XOR (conflict-free)

  const ushort_t* xa = xg + (size_t)srow * CDIM + sc * 8;
  const ushort_t* wa = wg + (size_t)srow * CDIM + sc * 8;

  #define STAGE_STEP(buf, ks) do {                                   \
    ushort_t* la_ = lds + (buf) * 8192;                              \
    ushort_t* lb_ = la_ + 4096;                                      \
    GLL16(xa + (ks),                  la_ + tid * 8);                \
    GLL16(xa + (ks) + 64 * CDIM,      la_ + 2048 + tid * 8);         \
    GLL16(wa + (ks),                  lb_ + tid * 8);                \
    GLL16(wa + (ks) + 64 * CDIM,      lb_ + 2048 + tid * 8);         \
  } while (0)

  STAGE_STEP(0, 0);
  #pragma unroll
  for (int s = 0; s < 12; ++s) {
    const int cur = s & 1;
    if (s < 11) {
      STAGE_STEP(cur ^ 1, (s + 1) * 32);
      asm volatile("s_waitcnt vmcnt(4)" ::: "memory");
    } else {
      asm volatile("s_waitcnt vmcnt(0)" ::: "memory");
    }
    __builtin_amdgcn_s_barrier();
    asm volatile("" ::: "memory");
    const ushort_t* la = lds + cur * 8192;
    const ushort_t* lb = la + 4096;
    bf16x8 aF[4], bF[4];
    #pragma unroll
    for (int i = 0; i < 4; ++i)
      aF[i] = *(const bf16x8*)(la + (wm * 64 + l15) * 32 + i * 512 + (quad ^ sx) * 8);
    #pragma unroll
    for (int j = 0; j < 4; ++j)
      bF[j] = *(const bf16x8*)(lb + (wn * 64 + l15) * 32 + j * 512 + (quad ^ sx) * 8);
    #pragma unroll
    for (int i = 0; i < 4; ++i)
      #pragma unroll
      for (int j = 0; j < 4; ++j)
        acc[i][j] = __builtin_amdgcn_mfma_f32_16x16x32_bf16(aF[i], bF[j], acc[i][j], 0, 0, 0);
    asm volatile("" ::: "memory");
    __builtin_amdgcn_s_barrier();
  }
  #undef STAGE_STEP
}

// prep: sniff dtype, convert x/W -> swizzled bf16 buffers (chunk c -> c^((row>>1)&3))
__global__ __launch_bounds__(256) void prep(const void* __restrict__ x,
                                            const void* __restrict__ qkw) {
  __shared__ int sflag;
  const int tid = threadIdx.x;
  if (tid < 64) {
    ushort_t u = ((const ushort_t*)x)[tid];
    int e = (u >> 7) & 0xFF;
    int ok = (e >= 117 && e <= 136) ? 1 : 0;
    unsigned long long m = __ballot(ok);
    if (tid == 0) {
      int f = (__popcll(m) >= 52) ? 0 : 1;
      sflag = f;
      if (blockIdx.x == 0) g_flag = f;
    }
  }
  __syncthreads();
  const bool fp32 = (sflag != 0);
  const int gid = blockIdx.x * 256 + tid;

  if (gid < 768 * 48) {
    const int oc = gid / 48, ck = gid - oc * 48;
    u16x8 t = cvt8(qkw, (size_t)gid * 8, fp32);
    const int ckp = (ck & ~3) | ((ck & 3) ^ ((oc >> 1) & 3));
    *(u16x8*)(g_wbf + (size_t)oc * CDIM + ckp * 8) = t;
  }
  const int total = 16 * 4096 * 48;
  for (int c = gid; c < total; c += 2048 * 256) {
    const int n = c / 48, ck = c - n * 48;
    u16x8 t = cvt8(x, (size_t)c * 8, fp32);
    const int ckp = (ck & ~3) | ((ck & 3) ^ ((n >> 1) & 3));
    *(u16x8*)(g_xbf + (size_t)n * CDIM + ckp * 8) = t;
  }
}

// Kernel 1: k = elu(x@Wk^T + bk)+1 ; ksum partial ; rope(k)->kropeT ;
//           kv partial = krope^T v via MFMA (v from g_xbf, transposed in LDS)
__global__ __launch_bounds__(256) void k1(const void* __restrict__ qkb)
{
  __shared__ __align__(16) char smem[53248];
  ushort_t* xs = (ushort_t*)smem;                // gemm dbuf: 32KB
  ushort_t* kropeT = (ushort_t*)smem;            // after GEMM: [128 ch][136] bf16 (34816 B)
  ushort_t* vT = (ushort_t*)(smem + 34816);      // [128 ch][72] bf16 (18432 B)

  const bool fp32 = (g_flag != 0);
  const int tid = threadIdx.x;
  const int nt = blockIdx.x, ct = blockIdx.y, b = blockIdx.z;

  f32x4 acc[4][4];
  gemm128c(g_xbf + ((size_t)b * NTOK + (size_t)nt * 128) * CDIM,
           g_wbf + (size_t)(CDIM + ct * 128) * CDIM, xs, tid, acc);

  const int lane = tid & 63, quad = lane >> 4, l15 = lane & 15;
  const int wv = tid >> 6, wm = wv >> 1, wn = wv & 1;

  // bias + elu + 1
  #pragma unroll
  for (int j = 0; j < 4; ++j) {
    const float bj = ldf(qkb, CDIM + ct * 128 + wn * 64 + j * 16 + l15, fp32);
    #pragma unroll
    for (int i = 0; i < 4; ++i)
      #pragma unroll
      for (int r = 0; r < 4; ++r) {
        float v = acc[i][j][r] + bj;
        acc[i][j][r] = v > 0.f ? v + 1.f : __expf(v);
      }
  }

  // unroped column sums -> ksum partial (plain store, no atomics)
  #pragma unroll
  for (int j = 0; j < 4; ++j) {
    float s = 0.f;
    #pragma unroll
    for (int i = 0; i < 4; ++i)
      #pragma unroll
      for (int r = 0; r < 4; ++r) s += acc[i][j][r];
    s += __shfl_down(s, 32);
    s += __shfl_down(s, 16);
    if (lane < 16)
      g_kspart[(size_t)(((b * 3 + ct) * 32 + nt) * 2 + wm) * 128 + wn * 64 + j * 16 + l15] = s;
  }

  // rope -> kropeT (transposed: [ch][tok], stride 136)
  float th[4]; bool sel[4];
  #pragma unroll
  for (int j = 0; j < 4; ++j) {
    int o = ct * 128 + wn * 64 + j * 16 + l15;
    int p = o >> 1;
    sel[j] = p < 96;
    int jj = sel[j] ? p : p - 96;
    th[j] = exp2f(-0.13841367062030676f * (float)jj);
  }
  #pragma unroll
  for (int i = 0; i < 4; ++i)
    #pragma unroll
    for (int r = 0; r < 4; ++r) {
      const int row  = wm * 64 + i * 16 + quad * 4 + r;
      const int ntok = nt * 128 + row;
      const float hhf = (float)(ntok >> 6), wwf = (float)(ntok & 63);
      #pragma unroll
      for (int j = 0; j < 4; ++j) {
        float ang = (sel[j] ? hhf : wwf) * th[j];
        float sn, cs;
        __sincosf(ang, &sn, &cs);
        float v0 = acc[i][j][r];
        float other = __shfl_xor(v0, 1);
        if (!(lane & 1)) {
          const int o = wn * 64 + j * 16 + l15;   // even channel
          kropeT[o * 136 + row]       = f2bf(cs * v0 - sn * other);
          kropeT[(o + 1) * 136 + row] = f2bf(sn * v0 + cs * other);
        }
      }
    }

  // kv via MFMA: kv[dd][e] = sum_n kropeT[dd][n] * vT[e][n], one head per wave
  const int hl = wv;
  f32x4 zz = {0.f, 0.f, 0.f, 0.f};
  f32x4 acc2[2][2];
  acc2[0][0] = zz; acc2[0][1] = zz; acc2[1][0] = zz; acc2[1][1] = zz;

  #pragma unroll
  for (int h = 0; h < 2; ++h) {
    __syncthreads();   // h=0: kropeT ready; h=1: previous half's vT reads done
    // stage vT for tokens h*64..h*64+63 from g_xbf (reg transpose)
    const int t64 = tid & 63;
    const size_t nrow = (size_t)b * NTOK + (size_t)nt * 128 + h * 64 + t64;
    #pragma unroll
    for (int it = 0; it < 4; ++it) {
      const int g = it * 4 + wv;          // ch-group 0..15
      const int ckt = ct * 16 + g;
      const int ckp = (ckt & ~3) | ((ckt & 3) ^ ((int)(nrow >> 1) & 3));
      u16x8 vv = *(const u16x8*)(g_xbf + nrow * CDIM + ckp * 8);
      #pragma unroll
      for (int i = 0; i < 8; ++i) vT[(g * 8 + i) * 72 + t64] = vv[i];
    }
    __syncthreads();
    #pragma unroll
    for (int ks = 0; ks < 2; ++ks) {
      bf16x8 a0 = *(const bf16x8*)(kropeT + (hl * 32 + l15) * 136      + h * 64 + ks * 32 + quad * 8);
      bf16x8 a1 = *(const bf16x8*)(kropeT + (hl * 32 + 16 + l15) * 136 + h * 64 + ks * 32 + quad * 8);
      bf16x8 b0 = *(const bf16x8*)(vT + (hl * 32 + l15) * 72      + ks * 32 + quad * 8);
      bf16x8 b1 = *(const bf16x8*)(vT + (hl * 32 + 16 + l15) * 72 + ks * 32 + quad * 8);
      acc2[0][0] = __builtin_amdgcn_mfma_f32_16x16x32_bf16(a0, b0, acc2[0][0], 0, 0, 0);
      acc2[0][1] = __builtin_amdgcn_mfma_f32_16x16x32_bf16(a0, b1, acc2[0][1], 0, 0, 0);
      acc2[1][0] = __builtin_amdgcn_mfma_f32_16x16x32_bf16(a1, b0, acc2[1][0], 0, 0, 0);
      acc2[1][1] = __builtin_amdgcn_mfma_f32_16x16x32_bf16(a1, b1, acc2[1][1], 0, 0, 0);
    }
  }

  float* dst = g_part + ((size_t)(((b * 3 + ct) * 32 + nt) * 4 + hl)) * 1024;
  #pragma unroll
  for (int mt = 0; mt < 2; ++mt)
    #pragma unroll
    for (int n2 = 0; n2 < 2; ++n2)
      #pragma unroll
      for (int r = 0; r < 4; ++r)
        dst[(mt * 16 + quad * 4 + r) * 32 + n2 * 16 + l15] = acc2[mt][n2][r];
}

// reduction: kv = sum_nt partials ; ksum = sum_{nt,wm} partials
__global__ __launch_bounds__(256) void red() {
  const int t = blockIdx.x * 256 + threadIdx.x;
  if (blockIdx.x < 192) {
    const int o = t * 4;
    const int b = o / 12288, r = o - b * 12288;
    const int h = r >> 10, off = r & 1023;
    const int ct = h >> 2, hl = h & 3;
    const float* p = g_part + ((size_t)((b * 3 + ct) * 32) * 4 + hl) * 1024 + off;
    f32x4 s = {0.f, 0.f, 0.f, 0.f};
    #pragma unroll 8
    for (int nt = 0; nt < 32; ++nt) {
      f32x4 v = *(const f32x4*)(p + (size_t)nt * 4096);
      s[0] += v[0]; s[1] += v[1]; s[2] += v[2]; s[3] += v[3];
    }
    *(f32x4*)(g_scr + (size_t)b * 12288 + h * 1024 + off) = s;
  } else {
    const int s4 = (t - 192 * 256) * 4;
    if (s4 < 16 * 384) {
      const int b = s4 / 384, ch = s4 - b * 384;
      const int ct = ch >> 7, chl = ch & 127;
      const float* p = g_kspart + (size_t)((b * 3 + ct) * 32) * 256 + chl;
      f32x4 s = {0.f, 0.f, 0.f, 0.f};
      #pragma unroll 8
      for (int nt = 0; nt < 32; ++nt) {
        f32x4 v0 = *(const f32x4*)(p + nt * 256);
        f32x4 v1 = *(const f32x4*)(p + nt * 256 + 128);
        s[0] += v0[0] + v1[0]; s[1] += v0[1] + v1[1];
        s[2] += v0[2] + v1[2]; s[3] += v0[3] + v1[3];
      }
      *(f32x4*)(g_scr + KV_FLOATS + (size_t)b * 384 + ch) = s;
    }
  }
}

// Kernel 2: q = elu(x@Wq^T + bq)+1 ; z = 1/(q . kmean + eps) ; rope(q) ;
//           out = z * (q_rope @ kv/n) + LePE(v), fused per row-half, coalesced stores
__global__ __launch_bounds__(256) void k2(const void* __restrict__ x,
                                          const void* __restrict__ qkb,
                                          const void* __restrict__ lepw,
                                          const void* __restrict__ lepb,
                                          void* __restrict__ out)
{
  __shared__ __align__(16) char smem[50176];
  ushort_t* xs  = (ushort_t*)smem;             // gemm dbuf: 32KB
  ushort_t* qr  = (ushort_t*)smem;             // after GEMM: [128][136] bf16 (34816 B)
  float* lepL = (float*)smem;                  // after aF loads: [64][132] fp32 (33792 B)
  ushort_t* kvT = (ushort_t*)(smem + 34816);   // [4][e=32][dd=32] bf16
  float* zl = (float*)(smem + 43008);          // [128][4]
  float* lw = (float*)(smem + 45056);          // [128][9]
  float* lb = (float*)(smem + 49664);          // [128]

  const bool fp32 = (g_flag != 0);
  const int tid = threadIdx.x;
  const int nt = blockIdx.x, ct = blockIdx.y, b = blockIdx.z;
  const float* kv_g   = g_scr;
  const float* ksum_g = g_scr + KV_FLOATS;

  for (int g = tid; g < 1152; g += 256) lw[g] = ldf(lepw, (size_t)ct * 1152 + g, fp32);
  if (tid < 128) lb[tid] = ldf(lepb, ct * 128 + tid, fp32);

  f32x4 acc[4][4];
  gemm128c(g_xbf + ((size_t)b * NTOK + (size_t)nt * 128) * CDIM,
           g_wbf + (size_t)(ct * 128) * CDIM, xs, tid, acc);

  const int lane = tid & 63, quad = lane >> 4, l15 = lane & 15;
  const int wv = tid >> 6, wm = wv >> 1, wn = wv & 1;

  // bias + elu + 1
  #pragma unroll
  for (int j = 0; j < 4; ++j) {
    const float bj = ldf(qkb, ct * 128 + wn * 64 + j * 16 + l15, fp32);
    #pragma unroll
    for (int i = 0; i < 4; ++i)
      #pragma unroll
      for (int r = 0; r < 4; ++r) {
        float v = acc[i][j][r] + bj;
        acc[i][j][r] = v > 0.f ? v + 1.f : __expf(v);
      }
  }

  // z = 1/(q . kmean + 1e-6)
  float km[4];
  #pragma unroll
  for (int j = 0; j < 4; ++j)
    km[j] = ksum_g[b * CDIM + ct * 128 + wn * 64 + j * 16 + l15] * (1.f / 4096.f);
  #pragma unroll
  for (int i = 0; i < 4; ++i)
    #pragma unroll
    for (int r = 0; r < 4; ++r) {
      float p0 = acc[i][0][r] * km[0] + acc[i][1][r] * km[1];
      float p1 = acc[i][2][r] * km[2] + acc[i][3][r] * km[3];
      #pragma unroll
      for (int off = 8; off > 0; off >>= 1) {
        p0 += __shfl_down(p0, off, 16);
        p1 += __shfl_down(p1, off, 16);
      }
      if (l15 == 0) {
        int row = wm * 64 + i * 16 + quad * 4 + r;
        zl[row * 4 + wn * 2]     = 1.f / (p0 + 1e-6f);
        zl[row * 4 + wn * 2 + 1] = 1.f / (p1 + 1e-6f);
      }
    }

  // rope -> qr (bf16, stride 136)
  float th[4]; bool sel[4];
  #pragma unroll
  for (int j = 0; j < 4; ++j) {
    int o = ct * 128 + wn * 64 + j * 16 + l15;
    int p = o >> 1;
    sel[j] = p < 96;
    int jj = sel[j] ? p : p - 96;
    th[j] = exp2f(-0.13841367062030676f * (float)jj);
  }
  #pragma unroll
  for (int i = 0; i < 4; ++i)
    #pragma unroll
    for (int r = 0; r < 4; ++r) {
      const int row  = wm * 64 + i * 16 + quad * 4 + r;
      const int ntok = nt * 128 + row;
      const float hhf = (float)(ntok >> 6), wwf = (float)(ntok & 63);
      #pragma unroll
      for (int j = 0; j < 4; ++j) {
        float ang = (sel[j] ? hhf : wwf) * th[j];
        float sn, cs;
        __sincosf(ang, &sn, &cs);
        float v0 = acc[i][j][r];
        float other = __shfl_xor(v0, 1);
        if (!(lane & 1)) {
          ushort2 t = make_ushort2(f2bf(cs * v0 - sn * other), f2bf(sn * v0 + cs * other));
          *(ushort2*)(qr + row * 136 + wn * 64 + j * 16 + l15) = t;
        }
      }
    }

  // stage kv (scaled 1/n) into LDS as bf16 [h][e][dd]
  const float* kvb = kv_g + (size_t)(b * NHEAD + ct * 4) * 1024;
  #pragma unroll
  for (int s = 0; s < 16; ++s) {
    int g = s * 256 + tid;
    int hl2 = g >> 10, dd = (g >> 5) & 31, e = g & 31;
    kvT[hl2 * 1024 + e * 32 + dd] = f2bf(kvb[g] * (1.f / 4096.f));
  }
  __syncthreads();

  // load all A-fragments up front -> qr dead afterwards
  const int hl = tid >> 6;
  bf16x8 aF[8];
  #pragma unroll
  for (int i = 0; i < 8; ++i)
    aF[i] = *(const bf16x8*)(qr + (i * 16 + l15) * 136 + hl * 32 + quad * 8);
  __syncthreads();   // all waves done reading qr; lepL region free

  // LePE thread mapping: 4 consecutive channels x 8 columns
  const int cc  = tid & 31;
  const int ch4 = cc * 4;
  const int gg  = tid >> 5;
  const int w0  = gg * 8;
  const float lbv0 = lb[ch4], lbv1 = lb[ch4 + 1], lbv2 = lb[ch4 + 2], lbv3 = lb[ch4 + 3];

  #pragma unroll
  for (int h = 0; h < 2; ++h) {
    if (h) __syncthreads();          // pass-0 lepL reads done before overwrite

    // out-projection for rows h*64..h*64+63, one head per wave
    f32x4 zzv = {0.f, 0.f, 0.f, 0.f};
    f32x4 oac4[4][2];
    #pragma unroll
    for (int iloc = 0; iloc < 4; ++iloc) { oac4[iloc][0] = zzv; oac4[iloc][1] = zzv; }
    #pragma unroll
    for (int jn = 0; jn < 2; ++jn) {
      bf16x8 bF = *(const bf16x8*)(kvT + hl * 1024 + (jn * 16 + l15) * 32 + quad * 8);
      #pragma unroll
      for (int iloc = 0; iloc < 4; ++iloc)
        oac4[iloc][jn] = __builtin_amdgcn_mfma_f32_16x16x32_bf16(aF[h * 4 + iloc], bF, oac4[iloc][jn], 0, 0, 0);
    }
    // attention result * z -> lepL [64 rows][132 ch]
    #pragma unroll
    for (int iloc = 0; iloc < 4; ++iloc)
      #pragma unroll
      for (int jn = 0; jn < 2; ++jn)
        #pragma unroll
        for (int r = 0; r < 4; ++r) {
          const int rowloc = iloc * 16 + quad * 4 + r;
          lepL[rowloc * 132 + hl * 32 + jn * 16 + l15] =
              oac4[iloc][jn][r] * zl[(h * 64 + rowloc) * 4 + hl];
        }
    __syncthreads();

    // LePE for image row hh, add attention, coalesced store
    const int hh = nt * 2 + h;
    float accv[8][4];
    #pragma unroll
    for (int s = 0; s < 8; ++s) {
      accv[s][0] = lbv0; accv[s][1] = lbv1; accv[s][2] = lbv2; accv[s][3] = lbv3;
    }
    #pragma unroll
    for (int rk = 0; rk < 3; ++rk) {
      const int ih = hh + rk - 1;
      if ((unsigned)ih < 64u) {      // wave-uniform branch
        float wr0[4], wr1[4], wr2[4];
        #pragma unroll
        for (int c = 0; c < 4; ++c) {
          wr0[c] = lw[(ch4 + c) * 9 + rk * 3 + 0];
          wr1[c] = lw[(ch4 + c) * 9 + rk * 3 + 1];
          wr2[c] = lw[(ch4 + c) * 9 + rk * 3 + 2];
        }
        const size_t rowbase = ((size_t)b * NTOK + (size_t)(ih * 64)) * CDIM
                             + (size_t)ct * 128 + ch4;
        float av[4], bv[4], cv[4];
        if (w0 > 0) load4(x, rowbase + (size_t)(w0 - 1) * CDIM, fp32, av);
        else { av[0] = av[1] = av[2] = av[3] = 0.f; }
        load4(x, rowbase + (size_t)w0 * CDIM, fp32, bv);
        #pragma unroll
        for (int s = 0; s < 8; ++s) {
          const int iwn = w0 + s + 1;
          if (iwn < 64) load4(x, rowbase + (size_t)iwn * CDIM, fp32, cv);
          else { cv[0] = cv[1] = cv[2] = cv[3] = 0.f; }
          #pragma unroll
          for (int c = 0; c < 4; ++c)
            accv[s][c] += wr0[c] * av[c] + wr1[c] * bv[c] + wr2[c] * cv[c];
          #pragma unroll
          for (int c = 0; c < 4; ++c) { av[c] = bv[c]; bv[c] = cv[c]; }
        }
      }
    }
    #pragma unroll
    for (int s = 0; s < 8; ++s) {
      f32x4 a = *(const f32x4*)(lepL + (w0 + s) * 132 + ch4);
      float r0 = accv[s][0] + a[0];
      float r1 = accv[s][1] + a[1];
      float r2 = accv[s][2] + a[2];
      float r3 = accv[s][3] + a[3];
      const size_t oi = ((size_t)b * NTOK + (size_t)(nt * 128 + h * 64 + w0 + s)) * CDIM
                      + (size_t)ct * 128 + ch4;
      if (fp32) {
        f32x4 t; t[0] = r0; t[1] = r1; t[2] = r2; t[3] = r3;
        *(f32x4*)((float*)out + oi) = t;
      } else {
        u16x4 t; t[0] = f2bf(r0); t[1] = f2bf(r1); t[2] = f2bf(r2); t[3] = f2bf(r3);
        *(u16x4*)((ushort_t*)out + oi) = t;
      }
    }
  }
}

extern "C" void kernel_launch(void* const* d_in, const int* in_sizes, int n_in,
                              void* d_out, int out_size, void* d_ws, size_t ws_size,
                              hipStream_t stream) {
  const void* x    = d_in[0];
  const void* qkw  = d_in[1];
  const void* qkb  = d_in[2];
  const void* lepw = d_in[3];
  const void* lepb = d_in[4];

  prep<<<2048, 256, 0, stream>>>(x, qkw);
  dim3 grid(32, 3, 16), blk(256, 1, 1);
  k1<<<grid, blk, 0, stream>>>(qkb);
  red<<<198, 256, 0, stream>>>();
  k2<<<grid, blk, 0, stream>>>(x, qkb, lepw, lepb, d_out);
}